// Round 13
// baseline (348.365 us; speedup 1.0000x reference)
//
#include <hip/hip_runtime.h>
#include <hip/hip_bf16.h>

#define BB   2048
#define TT   240
#define DD   90
#define MM   (BB*TT)          // 491520
#define KDIM (TT*DD)          // 21600
#define NCLS 40
#define NPAD 48               // k2 N padded to 3 MFMA col-tiles
#define KS2  45               // k2 split-K chunks
#define KST  15               // k-steps (x32) per chunk: 45*15*32 = 21600
#define WSTRIDE 92            // W LDS row stride: 90 W + 2 bias slots
#define WELEMS  26512         // 288*92 + 16-elem pad, 8-divisible (53024 B LDS)

typedef __bf16 bf16x8 __attribute__((ext_vector_type(8)));
typedef float  f32x4  __attribute__((ext_vector_type(4)));

#define LOG2E  1.44269504f
#define LOG2E2 2.88539008f

__device__ __forceinline__ bf16x8 cvt8(float4 a, float4 b){
    bf16x8 r;
    r[0]=(__bf16)a.x; r[1]=(__bf16)a.y; r[2]=(__bf16)a.z; r[3]=(__bf16)a.w;
    r[4]=(__bf16)b.x; r[5]=(__bf16)b.y; r[6]=(__bf16)b.z; r[7]=(__bf16)b.w;
    return r;
}

__device__ __forceinline__ unsigned pack_bf16(float a, float b){
    unsigned u0 = (unsigned)__builtin_bit_cast(unsigned short, (__bf16)a);
    unsigned u1 = (unsigned)__builtin_bit_cast(unsigned short, (__bf16)b);
    return u0 | (u1 << 16);
}

// ---------------------------------------------------------------------------
// pack1: W rows PRE-SCALED by the exp2 constants (i,o: -log2e; g: 2*log2e)
// so the epilogue's exp2f args come straight from the accumulators.
// Layout: wtb flat [288][92]: k<90 = scaled W, k=90 bias-hi, k=91 bias-lo.
// Rows c = g*96 + dd (gates i,g,o); dd in [90,96) zero rows.
// ---------------------------------------------------------------------------
__global__ void pack1(const float* __restrict__ Wih,
                      const float* __restrict__ bih,
                      const float* __restrict__ bhh,
                      __bf16* __restrict__ wtb)
{
    int id = blockIdx.x*256 + threadIdx.x;     // 8 elems per thread
    if (id >= WELEMS/8) return;
    bf16x8 v;
    #pragma unroll
    for (int e = 0; e < 8; ++e){
        int el = id*8 + e;
        int c  = el / WSTRIDE;
        int k  = el - c*WSTRIDE;
        float f = 0.f;
        if (c < 288){
            int g = c / 96, dd = c - g*96;
            if (dd < 90){
                int row = (g==0 ? dd : (g==1 ? 180+dd : 270+dd));
                float scale = (g==1) ? LOG2E2 : -LOG2E;
                if (k < 90){
                    f = scale * Wih[row*90 + k];
                } else {
                    float bv  = scale * (bih[row] + bhh[row]);
                    float bhi = (float)(__bf16)bv;
                    f = (k == 90) ? bhi : (bv - bhi);
                }
            }
        }
        v[e] = (__bf16)f;
    }
    *(bf16x8*)(wtb + id*8) = v;
}

// ---------------------------------------------------------------------------
// pack2: hi/lo bf16 split of W_out (compensated bf16). [48][21600] each.
// ---------------------------------------------------------------------------
__global__ void pack2(const float* __restrict__ W2,
                      __bf16* __restrict__ w2hi,
                      __bf16* __restrict__ w2lo)
{
    int id = blockIdx.x*256 + threadIdx.x;
    if (id >= NPAD*2700) return;
    int n  = id / 2700;
    int k8 = id - n*2700;
    bf16x8 vh, vl;
    if (n < NCLS){
        #pragma unroll
        for (int e = 0; e < 8; ++e){
            float f = W2[(size_t)n*KDIM + k8*8 + e];
            __bf16 hb = (__bf16)f;
            vh[e] = hb;
            vl[e] = (__bf16)(f - (float)hb);
        }
    } else {
        #pragma unroll
        for (int e = 0; e < 8; ++e){ vh[e] = (__bf16)0.f; vl[e] = (__bf16)0.f; }
    }
    *(bf16x8*)(w2hi + (size_t)n*KDIM + k8*8) = vh;
    *(bf16x8*)(w2lo + (size_t)n*KDIM + k8*8) = vl;
}

// ---------------------------------------------------------------------------
// k1: gates GEMM via MFMA, C^T orientation (r9 structure, VERIFIED).
// Occupancy squeeze: W LDS stride 104->92 (53.0 KB -> 3 blocks/CU = 159 KB)
// + __launch_bounds__(512,6) (VGPR cap 85) -> 6 waves/SIMD vs r9's 4.
// kg=3,ks=2 ds_read_b128 overruns 8 bf16 into the next row: harmless,
// those af lanes are ZERO (garbage*0); +16-elem tail pad covers row 287.
// exp2-scale constants folded into W (pack1): 3 fewer v_mul per h.
// ---------------------------------------------------------------------------
__global__ __launch_bounds__(512, 6)
void k1_gates(const float* __restrict__ x,
              const __bf16* __restrict__ wtb,
              __bf16* __restrict__ h)
{
    __shared__ __align__(16) __bf16 wt[WELEMS];    // 53024 B -> 3 blocks/CU

    const int tid  = threadIdx.x;
    const int lane = tid & 63;
    const int wv   = tid >> 6;      // 0..7
    const int rg   = wv >> 1;       // row group 0..3
    const int nh   = wv & 1;        // N half 0..1
    const int l15  = lane & 15;
    const int kg   = lane >> 4;     // 0..3

    // stage W (flat copy, layout identical global->LDS)
    {
        const float4* src = (const float4*)wtb;
        float4* dst = (float4*)wt;
        #pragma unroll
        for (int i = 0; i < 7; ++i){
            int idx = tid + i*512;
            if (idx < WELEMS/8) dst[idx] = src[idx];
        }
    }
    __syncthreads();

    const int tbase = blockIdx.x * 15;     // 512 blocks * 15 tiles * 64 rows

    // x loads: lane (l15,kg) reads row (rg*16 + l15), k = ks*32 + kg*8 + e
    float4 xr[6];
    float2 xe;
    {
        const float* p = x + ((size_t)tbase*64 + rg*16 + l15)*90;
        #pragma unroll
        for (int ks = 0; ks < 2; ++ks){
            xr[ks*2+0] = *(const float4*)(p + ks*32 + kg*8);
            xr[ks*2+1] = *(const float4*)(p + ks*32 + kg*8 + 4);
        }
        if (kg < 3){
            xr[4] = *(const float4*)(p + 64 + kg*8);
            xr[5] = *(const float4*)(p + 64 + kg*8 + 4);
        } else {
            xe = *(const float2*)(p + 88);
        }
    }

    for (int t = 0; t < 15; ++t){
        // cvt prefetched f32 -> bf16 x-frags (first use waits vmcnt)
        bf16x8 af[3];
        af[0] = cvt8(xr[0], xr[1]);
        af[1] = cvt8(xr[2], xr[3]);
        if (kg < 3){
            af[2] = cvt8(xr[4], xr[5]);
        } else {
            // kg=3 covers k=88..95: x88, x89, 1.0 at k=90,91 (bias rows), 0s
            bf16x8 z;
            #pragma unroll
            for (int e = 0; e < 8; ++e) z[e] = (__bf16)0.f;
            z[0] = (__bf16)xe.x; z[1] = (__bf16)xe.y;
            z[2] = (__bf16)1.0f; z[3] = (__bf16)1.0f;
            af[2] = z;
        }

        f32x4 acc[3][3];
        #pragma unroll
        for (int g = 0; g < 3; ++g)
            #pragma unroll
            for (int j = 0; j < 3; ++j) acc[g][j] = f32x4{0.f,0.f,0.f,0.f};

        // W-frags: wt row c = g*96 + nh*48 + j*16 + l15, stride 92
        // SWAPPED operands: mfma(W, x, acc) -> C row = dd_local, col = m_local
        const __bf16* wbase = wt + (nh*48 + l15)*WSTRIDE + 8*kg;
        #pragma unroll
        for (int g = 0; g < 3; ++g){
            #pragma unroll
            for (int j = 0; j < 3; ++j){
                const __bf16* wrow = wbase + (g*96 + j*16)*WSTRIDE;
                #pragma unroll
                for (int ks = 0; ks < 3; ++ks){
                    bf16x8 wv8 = *(const bf16x8*)(wrow + ks*32);
                    acc[g][j] = __builtin_amdgcn_mfma_f32_16x16x32_bf16(wv8, af[ks], acc[g][j], 0,0,0);
                }
            }
        }

        // issue next tile's x loads; MFMA+epilogue hide the latency
        if (t < 14){
            const float* p = x + ((size_t)(tbase+t+1)*64 + rg*16 + l15)*90;
            #pragma unroll
            for (int ks = 0; ks < 2; ++ks){
                xr[ks*2+0] = *(const float4*)(p + ks*32 + kg*8);
                xr[ks*2+1] = *(const float4*)(p + ks*32 + kg*8 + 4);
            }
            if (kg < 3){
                xr[4] = *(const float4*)(p + 64 + kg*8);
                xr[5] = *(const float4*)(p + 64 + kg*8 + 4);
            } else {
                xe = *(const float2*)(p + 88);
            }
        }

        // epilogue: lane owns m-row (l15); acc[g][j][r] -> dd = nh*48+j*16+kg*4+r
        // accs are PRE-SCALED: acc0 = -log2e*(i+b), acc1 = 2log2e*(g+b),
        // acc2 = -log2e*(o+b) -> exp2f args direct.
        const size_t mrow = (size_t)(tbase+t)*64 + rg*16 + l15;
        __bf16* hp = h + mrow*90;
        #pragma unroll
        for (int j = 0; j < 3; ++j){
            int dd0 = nh*48 + j*16 + kg*4;
            float hv[4];
            #pragma unroll
            for (int r = 0; r < 4; ++r){
                float ea = exp2f(acc[0][j][r]);
                float Eg = exp2f(acc[1][j][r]);
                float cc = (Eg - 1.f) * __builtin_amdgcn_rcpf((1.f + ea)*(Eg + 1.f));
                float eo = exp2f(acc[2][j][r]);
                float Ec = exp2f(LOG2E2*cc);
                hv[r] = (Ec - 1.f) * __builtin_amdgcn_rcpf((1.f + eo)*(Ec + 1.f));
            }
            if (dd0 < 90)
                *(unsigned*)(hp + dd0) = pack_bf16(hv[0], hv[1]);
            if (dd0 + 2 < 90)
                *(unsigned*)(hp + dd0 + 2) = pack_bf16(hv[2], hv[3]);
        }
    }
}

// ---------------------------------------------------------------------------
// k2: out GEMM [2048 x 21600] @ [21600 x 48] via MFMA, split-K 45.
// ---------------------------------------------------------------------------
__global__ __launch_bounds__(256)
void k2_out(const __bf16* __restrict__ h,
            const __bf16* __restrict__ w2hi,
            const __bf16* __restrict__ w2lo,
            float* __restrict__ part2)
{
    const int tid  = threadIdx.x;
    const int lane = tid & 63;
    const int wv   = tid >> 6;
    const int l15  = lane & 15;
    const int kg   = lane >> 4;
    const int m0   = (blockIdx.x*4 + wv) * 32;       // 0..2016
    const int chunk= blockIdx.y;                     // 0..44
    const size_t kbase = (size_t)chunk*(KST*32) + 8*kg;

    const __bf16* ha = h    + (size_t)(m0 + l15)*KDIM + kbase;
    const __bf16* hb = ha   + (size_t)16*KDIM;
    const __bf16* h0 = w2hi + (size_t)l15*KDIM + kbase;
    const __bf16* h1 = h0   + (size_t)16*KDIM;
    const __bf16* h2 = h0   + (size_t)32*KDIM;
    const __bf16* l0 = w2lo + (size_t)l15*KDIM + kbase;
    const __bf16* l1 = l0   + (size_t)16*KDIM;
    const __bf16* l2 = l0   + (size_t)32*KDIM;

    f32x4 acc00 = {0.f,0.f,0.f,0.f}, acc01 = acc00, acc02 = acc00;
    f32x4 acc10 = acc00, acc11 = acc00, acc12 = acc00;

    #pragma unroll
    for (int s = 0; s < KST; ++s){
        bf16x8 a0  = *(const bf16x8*)(ha + s*32);
        bf16x8 a1  = *(const bf16x8*)(hb + s*32);
        bf16x8 bh0 = *(const bf16x8*)(h0 + s*32);
        bf16x8 bh1 = *(const bf16x8*)(h1 + s*32);
        bf16x8 bh2 = *(const bf16x8*)(h2 + s*32);
        bf16x8 bl0 = *(const bf16x8*)(l0 + s*32);
        bf16x8 bl1 = *(const bf16x8*)(l1 + s*32);
        bf16x8 bl2 = *(const bf16x8*)(l2 + s*32);
        acc00 = __builtin_amdgcn_mfma_f32_16x16x32_bf16(a0, bh0, acc00, 0,0,0);
        acc01 = __builtin_amdgcn_mfma_f32_16x16x32_bf16(a0, bh1, acc01, 0,0,0);
        acc02 = __builtin_amdgcn_mfma_f32_16x16x32_bf16(a0, bh2, acc02, 0,0,0);
        acc10 = __builtin_amdgcn_mfma_f32_16x16x32_bf16(a1, bh0, acc10, 0,0,0);
        acc11 = __builtin_amdgcn_mfma_f32_16x16x32_bf16(a1, bh1, acc11, 0,0,0);
        acc12 = __builtin_amdgcn_mfma_f32_16x16x32_bf16(a1, bh2, acc12, 0,0,0);
        acc00 = __builtin_amdgcn_mfma_f32_16x16x32_bf16(a0, bl0, acc00, 0,0,0);
        acc01 = __builtin_amdgcn_mfma_f32_16x16x32_bf16(a0, bl1, acc01, 0,0,0);
        acc02 = __builtin_amdgcn_mfma_f32_16x16x32_bf16(a0, bl2, acc02, 0,0,0);
        acc10 = __builtin_amdgcn_mfma_f32_16x16x32_bf16(a1, bl0, acc10, 0,0,0);
        acc11 = __builtin_amdgcn_mfma_f32_16x16x32_bf16(a1, bl1, acc11, 0,0,0);
        acc12 = __builtin_amdgcn_mfma_f32_16x16x32_bf16(a1, bl2, acc12, 0,0,0);
    }

    float* pp = part2 + (size_t)chunk*(BB*NPAD);
    const int rbase = kg*4;
    #pragma unroll
    for (int r = 0; r < 4; ++r){
        size_t row0 = (size_t)(m0 + rbase + r)*NPAD;
        size_t row1 = (size_t)(m0 + 16 + rbase + r)*NPAD;
        pp[row0 +      l15] = acc00[r];
        pp[row0 + 16 + l15] = acc01[r];
        pp[row0 + 32 + l15] = acc02[r];
        pp[row1 +      l15] = acc10[r];
        pp[row1 + 16 + l15] = acc11[r];
        pp[row1 + 32 + l15] = acc12[r];
    }
}

// ---------------------------------------------------------------------------
// k3 (fused): reduce split-K partials + bias, then softmax over groups of 10.
// 256 blocks x 384 thr = 8 b-rows x 48 n each; LDS handoff to 32 threads.
// ---------------------------------------------------------------------------
__global__ __launch_bounds__(384)
void k3(const float* __restrict__ part2,
        const float* __restrict__ bout,
        float* __restrict__ out)
{
    __shared__ float sm[8*NPAD];
    const int tid  = threadIdx.x;
    const int base = blockIdx.x * 8 * NPAD;      // flat (b*48+n) base

    {
        int g = base + tid;
        float s = 0.f;
        for (int c = 0; c < KS2; ++c) s += part2[(size_t)c*(BB*NPAD) + g];
        int n = tid % NPAD;
        sm[tid] = s + (n < NCLS ? bout[n] : 0.f);
    }
    __syncthreads();

    if (tid < 32){
        int lb  = tid >> 2;      // 0..7
        int grp = tid & 3;       // 0..3
        const float* lg = sm + lb*NPAD + grp*10;
        float v[10]; float mx = -1e30f;
        #pragma unroll
        for (int q = 0; q < 10; ++q){ v[q] = lg[q]; mx = fmaxf(mx, v[q]); }
        float e[10]; float s = 0.f;
        #pragma unroll
        for (int q = 0; q < 10; ++q){ e[q] = __expf(v[q]-mx); s += e[q]; }
        float inv = 1.0f/s;
        size_t b = (size_t)blockIdx.x*8 + lb;
        #pragma unroll
        for (int q = 0; q < 10; ++q) out[b*NCLS + grp*10 + q] = e[q]*inv;
    }
}

// ---------------------------------------------------------------------------
extern "C" void kernel_launch(void* const* d_in, const int* in_sizes, int n_in,
                              void* d_out, int out_size, void* d_ws, size_t ws_size,
                              hipStream_t stream)
{
    const float* x    = (const float*)d_in[0];
    const float* Wih  = (const float*)d_in[1];
    // d_in[2] = W_hh unused (zero initial hidden state)
    const float* bih  = (const float*)d_in[3];
    const float* bhh  = (const float*)d_in[4];
    const float* W2   = (const float*)d_in[5];
    const float* bout = (const float*)d_in[6];
    float* out = (float*)d_out;

    char* ws = (char*)d_ws;
    size_t off = 0;
    auto alloc = [&](size_t bytes){ void* p = ws + off; off = (off + bytes + 255) & ~(size_t)255; return p; };
    __bf16* h     = (__bf16*)alloc((size_t)MM*DD*2);           // 88.5 MB
    float*  part2 = (float*) alloc((size_t)KS2*BB*NPAD*4);     // 17.7 MB
    __bf16* wtb   = (__bf16*)alloc((size_t)WELEMS*2);          // 53 KB
    __bf16* w2hi  = (__bf16*)alloc((size_t)NPAD*KDIM*2);       // 2.1 MB
    __bf16* w2lo  = (__bf16*)alloc((size_t)NPAD*KDIM*2);       // 2.1 MB

    pack1<<<(WELEMS/8 + 255)/256, 256, 0, stream>>>(Wih, bih, bhh, wtb);
    pack2<<<(NPAD*2700 + 255)/256, 256, 0, stream>>>(W2, w2hi, w2lo);
    k1_gates<<<512, 512, 0, stream>>>(x, wtb, h);
    k2_out<<<dim3(16, KS2), 256, 0, stream>>>(h, w2hi, w2lo, part2);
    k3<<<BB/8, 384, 0, stream>>>(part2, bout, out);
}

// Round 14
// 131.557 us; speedup vs baseline: 2.6480x; 2.6480x over previous
//
#include <hip/hip_runtime.h>
#include <hip/hip_bf16.h>

#define BB   2048
#define TT   240
#define DD   90
#define MM   (BB*TT)          // 491520
#define KDIM (TT*DD)          // 21600
#define NCLS 40
#define NPAD 48               // k2 N padded to 3 MFMA col-tiles
#define KS2  45               // k2 split-K chunks
#define KST  15               // k-steps (x32) per chunk: 45*15*32 = 21600

typedef __bf16 bf16x8 __attribute__((ext_vector_type(8)));
typedef float  f32x4  __attribute__((ext_vector_type(4)));

#define LOG2E  1.44269504f
#define LOG2E2 2.88539008f

__device__ __forceinline__ bf16x8 cvt8(float4 a, float4 b){
    bf16x8 r;
    r[0]=(__bf16)a.x; r[1]=(__bf16)a.y; r[2]=(__bf16)a.z; r[3]=(__bf16)a.w;
    r[4]=(__bf16)b.x; r[5]=(__bf16)b.y; r[6]=(__bf16)b.z; r[7]=(__bf16)b.w;
    return r;
}

__device__ __forceinline__ unsigned pack_bf16(float a, float b){
    unsigned u0 = (unsigned)__builtin_bit_cast(unsigned short, (__bf16)a);
    unsigned u1 = (unsigned)__builtin_bit_cast(unsigned short, (__bf16)b);
    return u0 | (u1 << 16);
}

// ---------------------------------------------------------------------------
// pack1 (r9 layout + r13 pre-scale, both verified): Wtb[c][k] bf16,
// c = g*96+dd (gates i,g,o), k padded 90->104. Rows PRE-SCALED by the exp2
// constants (i,o: -log2e; g: 2*log2e) so epilogue exp2f args come straight
// from accumulators. k=90: bias-hi, k=91: bias-lo (of scaled bias);
// x-frag supplies 1.0 there. k=92..103 zero. dd in [90,96): zero rows.
// ---------------------------------------------------------------------------
__global__ void pack1(const float* __restrict__ Wih,
                      const float* __restrict__ bih,
                      const float* __restrict__ bhh,
                      __bf16* __restrict__ wtb)
{
    int id = blockIdx.x*256 + threadIdx.x;
    if (id >= 288*13) return;
    int c  = id / 13;
    int k8 = id - c*13;
    int g  = c / 96, dd = c - g*96;
    int row = (g==0 ? dd : (g==1 ? 180+dd : 270+dd));
    float scale = (g==1) ? LOG2E2 : -LOG2E;
    float bv = 0.f, bhi = 0.f, blo = 0.f;
    if (dd < 90){
        bv  = scale * (bih[row] + bhh[row]);
        bhi = (float)(__bf16)bv;
        blo = bv - bhi;
    }
    bf16x8 v;
    #pragma unroll
    for (int e = 0; e < 8; ++e){
        int k = k8*8 + e;
        float f = 0.f;
        if (dd < 90){
            if (k < 90)       f = scale * Wih[row*90 + k];
            else if (k == 90) f = bhi;
            else if (k == 91) f = blo;
        }
        v[e] = (__bf16)f;
    }
    *(bf16x8*)(wtb + c*104 + k8*8) = v;
}

// ---------------------------------------------------------------------------
// pack2: hi/lo bf16 split of W_out (compensated bf16). [48][21600] each.
// ---------------------------------------------------------------------------
__global__ void pack2(const float* __restrict__ W2,
                      __bf16* __restrict__ w2hi,
                      __bf16* __restrict__ w2lo)
{
    int id = blockIdx.x*256 + threadIdx.x;
    if (id >= NPAD*2700) return;
    int n  = id / 2700;
    int k8 = id - n*2700;
    bf16x8 vh, vl;
    if (n < NCLS){
        #pragma unroll
        for (int e = 0; e < 8; ++e){
            float f = W2[(size_t)n*KDIM + k8*8 + e];
            __bf16 hb = (__bf16)f;
            vh[e] = hb;
            vl[e] = (__bf16)(f - (float)hb);
        }
    } else {
        #pragma unroll
        for (int e = 0; e < 8; ++e){ vh[e] = (__bf16)0.f; vl[e] = (__bf16)0.f; }
    }
    *(bf16x8*)(w2hi + (size_t)n*KDIM + k8*8) = vh;
    *(bf16x8*)(w2lo + (size_t)n*KDIM + k8*8) = vl;
}

// ---------------------------------------------------------------------------
// k1: r9 structure VERBATIM (the 105-us proven config: WSTRIDE 104 W in LDS,
// launch_bounds(512,2) -> VGPR ~96, no forced occupancy) + r13's verified
// direct-exp2 epilogue on pre-scaled accumulators.
// C^T orientation: mfma(W, x, acc) -> lane l15 = m-row,
// acc[g][j][r] -> dd = nh*48 + j*16 + kg*4 + r.
// ---------------------------------------------------------------------------
__global__ __launch_bounds__(512, 2)
void k1_gates(const float* __restrict__ x,
              const __bf16* __restrict__ wtb,
              __bf16* __restrict__ h)
{
    __shared__ __align__(16) __bf16 wt[288*104];   // 59904 B

    const int tid  = threadIdx.x;
    const int lane = tid & 63;
    const int wv   = tid >> 6;      // 0..7
    const int rg   = wv >> 1;       // row group 0..3
    const int nh   = wv & 1;        // N half 0..1
    const int l15  = lane & 15;
    const int kg   = lane >> 4;     // 0..3

    // stage W tile (bf16, packed/padded, pre-scaled, bias at k=90,91) -> LDS
    {
        const float4* src = (const float4*)wtb;
        float4* dst = (float4*)wt;
        #pragma unroll
        for (int i = 0; i < 8; ++i){
            int idx = tid + i*512;
            if (idx < 3744) dst[idx] = src[idx];
        }
    }
    __syncthreads();

    const int tbase = blockIdx.x * 15;     // 512 blocks * 15 tiles * 64 rows

    // x loads: lane (l15,kg) reads row (rg*16 + l15), k = ks*32 + kg*8 + e
    float4 xr[6];
    float2 xe;
    {
        const float* p = x + ((size_t)tbase*64 + rg*16 + l15)*90;
        #pragma unroll
        for (int ks = 0; ks < 2; ++ks){
            xr[ks*2+0] = *(const float4*)(p + ks*32 + kg*8);
            xr[ks*2+1] = *(const float4*)(p + ks*32 + kg*8 + 4);
        }
        if (kg < 3){
            xr[4] = *(const float4*)(p + 64 + kg*8);
            xr[5] = *(const float4*)(p + 64 + kg*8 + 4);
        } else {
            xe = *(const float2*)(p + 88);
        }
    }

    for (int t = 0; t < 15; ++t){
        // cvt prefetched f32 -> bf16 x-frags (first use waits vmcnt)
        bf16x8 af[3];
        af[0] = cvt8(xr[0], xr[1]);
        af[1] = cvt8(xr[2], xr[3]);
        if (kg < 3){
            af[2] = cvt8(xr[4], xr[5]);
        } else {
            // kg=3 covers k=88..95: x88, x89, then 1.0 at k=90,91 (bias rows)
            bf16x8 z;
            #pragma unroll
            for (int e = 0; e < 8; ++e) z[e] = (__bf16)0.f;
            z[0] = (__bf16)xe.x; z[1] = (__bf16)xe.y;
            z[2] = (__bf16)1.0f; z[3] = (__bf16)1.0f;
            af[2] = z;
        }

        f32x4 acc[3][3];
        #pragma unroll
        for (int g = 0; g < 3; ++g)
            #pragma unroll
            for (int j = 0; j < 3; ++j) acc[g][j] = f32x4{0.f,0.f,0.f,0.f};

        // W-frags: wt row c = g*96 + nh*48 + j*16 + l15, k-offset ks*32 + 8*kg
        const __bf16* wbase = wt + (nh*48 + l15)*104 + 8*kg;
        #pragma unroll
        for (int g = 0; g < 3; ++g){
            #pragma unroll
            for (int j = 0; j < 3; ++j){
                const __bf16* wrow = wbase + (g*96 + j*16)*104;
                #pragma unroll
                for (int ks = 0; ks < 3; ++ks){
                    bf16x8 wv8 = *(const bf16x8*)(wrow + ks*32);
                    acc[g][j] = __builtin_amdgcn_mfma_f32_16x16x32_bf16(wv8, af[ks], acc[g][j], 0,0,0);
                }
            }
        }

        // issue next tile's x loads; MFMA+epilogue hide the latency
        if (t < 14){
            const float* p = x + ((size_t)(tbase+t+1)*64 + rg*16 + l15)*90;
            #pragma unroll
            for (int ks = 0; ks < 2; ++ks){
                xr[ks*2+0] = *(const float4*)(p + ks*32 + kg*8);
                xr[ks*2+1] = *(const float4*)(p + ks*32 + kg*8 + 4);
            }
            if (kg < 3){
                xr[4] = *(const float4*)(p + 64 + kg*8);
                xr[5] = *(const float4*)(p + 64 + kg*8 + 4);
            } else {
                xe = *(const float2*)(p + 88);
            }
        }

        // epilogue (r13-verified math): accs pre-scaled ->
        // acc0 = -log2e*(i+b), acc1 = 2log2e*(g+b), acc2 = -log2e*(o+b)
        const size_t mrow = (size_t)(tbase+t)*64 + rg*16 + l15;
        __bf16* hp = h + mrow*90;
        #pragma unroll
        for (int j = 0; j < 3; ++j){
            int dd0 = nh*48 + j*16 + kg*4;
            float hv[4];
            #pragma unroll
            for (int r = 0; r < 4; ++r){
                float ea = exp2f(acc[0][j][r]);
                float Eg = exp2f(acc[1][j][r]);
                float cc = (Eg - 1.f) * __builtin_amdgcn_rcpf((1.f + ea)*(Eg + 1.f));
                float eo = exp2f(acc[2][j][r]);
                float Ec = exp2f(LOG2E2*cc);
                hv[r] = (Ec - 1.f) * __builtin_amdgcn_rcpf((1.f + eo)*(Ec + 1.f));
            }
            if (dd0 < 90)
                *(unsigned*)(hp + dd0) = pack_bf16(hv[0], hv[1]);
            if (dd0 + 2 < 90)
                *(unsigned*)(hp + dd0 + 2) = pack_bf16(hv[2], hv[3]);
        }
    }
}

// ---------------------------------------------------------------------------
// k2: out GEMM [2048 x 21600] @ [21600 x 48] via MFMA, split-K 45.
// ---------------------------------------------------------------------------
__global__ __launch_bounds__(256)
void k2_out(const __bf16* __restrict__ h,
            const __bf16* __restrict__ w2hi,
            const __bf16* __restrict__ w2lo,
            float* __restrict__ part2)
{
    const int tid  = threadIdx.x;
    const int lane = tid & 63;
    const int wv   = tid >> 6;
    const int l15  = lane & 15;
    const int kg   = lane >> 4;
    const int m0   = (blockIdx.x*4 + wv) * 32;       // 0..2016
    const int chunk= blockIdx.y;                     // 0..44
    const size_t kbase = (size_t)chunk*(KST*32) + 8*kg;

    const __bf16* ha = h    + (size_t)(m0 + l15)*KDIM + kbase;
    const __bf16* hb = ha   + (size_t)16*KDIM;
    const __bf16* h0 = w2hi + (size_t)l15*KDIM + kbase;
    const __bf16* h1 = h0   + (size_t)16*KDIM;
    const __bf16* h2 = h0   + (size_t)32*KDIM;
    const __bf16* l0 = w2lo + (size_t)l15*KDIM + kbase;
    const __bf16* l1 = l0   + (size_t)16*KDIM;
    const __bf16* l2 = l0   + (size_t)32*KDIM;

    f32x4 acc00 = {0.f,0.f,0.f,0.f}, acc01 = acc00, acc02 = acc00;
    f32x4 acc10 = acc00, acc11 = acc00, acc12 = acc00;

    #pragma unroll
    for (int s = 0; s < KST; ++s){
        bf16x8 a0  = *(const bf16x8*)(ha + s*32);
        bf16x8 a1  = *(const bf16x8*)(hb + s*32);
        bf16x8 bh0 = *(const bf16x8*)(h0 + s*32);
        bf16x8 bh1 = *(const bf16x8*)(h1 + s*32);
        bf16x8 bh2 = *(const bf16x8*)(h2 + s*32);
        bf16x8 bl0 = *(const bf16x8*)(l0 + s*32);
        bf16x8 bl1 = *(const bf16x8*)(l1 + s*32);
        bf16x8 bl2 = *(const bf16x8*)(l2 + s*32);
        acc00 = __builtin_amdgcn_mfma_f32_16x16x32_bf16(a0, bh0, acc00, 0,0,0);
        acc01 = __builtin_amdgcn_mfma_f32_16x16x32_bf16(a0, bh1, acc01, 0,0,0);
        acc02 = __builtin_amdgcn_mfma_f32_16x16x32_bf16(a0, bh2, acc02, 0,0,0);
        acc10 = __builtin_amdgcn_mfma_f32_16x16x32_bf16(a1, bh0, acc10, 0,0,0);
        acc11 = __builtin_amdgcn_mfma_f32_16x16x32_bf16(a1, bh1, acc11, 0,0,0);
        acc12 = __builtin_amdgcn_mfma_f32_16x16x32_bf16(a1, bh2, acc12, 0,0,0);
        acc00 = __builtin_amdgcn_mfma_f32_16x16x32_bf16(a0, bl0, acc00, 0,0,0);
        acc01 = __builtin_amdgcn_mfma_f32_16x16x32_bf16(a0, bl1, acc01, 0,0,0);
        acc02 = __builtin_amdgcn_mfma_f32_16x16x32_bf16(a0, bl2, acc02, 0,0,0);
        acc10 = __builtin_amdgcn_mfma_f32_16x16x32_bf16(a1, bl0, acc10, 0,0,0);
        acc11 = __builtin_amdgcn_mfma_f32_16x16x32_bf16(a1, bl1, acc11, 0,0,0);
        acc12 = __builtin_amdgcn_mfma_f32_16x16x32_bf16(a1, bl2, acc12, 0,0,0);
    }

    float* pp = part2 + (size_t)chunk*(BB*NPAD);
    const int rbase = kg*4;
    #pragma unroll
    for (int r = 0; r < 4; ++r){
        size_t row0 = (size_t)(m0 + rbase + r)*NPAD;
        size_t row1 = (size_t)(m0 + 16 + rbase + r)*NPAD;
        pp[row0 +      l15] = acc00[r];
        pp[row0 + 16 + l15] = acc01[r];
        pp[row0 + 32 + l15] = acc02[r];
        pp[row1 +      l15] = acc10[r];
        pp[row1 + 16 + l15] = acc11[r];
        pp[row1 + 32 + l15] = acc12[r];
    }
}

// ---------------------------------------------------------------------------
// k3 (fused): reduce split-K partials + bias, then softmax over groups of 10.
// 256 blocks x 384 thr = 8 b-rows x 48 n each; LDS handoff to 32 threads.
// ---------------------------------------------------------------------------
__global__ __launch_bounds__(384)
void k3(const float* __restrict__ part2,
        const float* __restrict__ bout,
        float* __restrict__ out)
{
    __shared__ float sm[8*NPAD];
    const int tid  = threadIdx.x;
    const int base = blockIdx.x * 8 * NPAD;      // flat (b*48+n) base

    {
        int g = base + tid;
        float s = 0.f;
        for (int c = 0; c < KS2; ++c) s += part2[(size_t)c*(BB*NPAD) + g];
        int n = tid % NPAD;
        sm[tid] = s + (n < NCLS ? bout[n] : 0.f);
    }
    __syncthreads();

    if (tid < 32){
        int lb  = tid >> 2;      // 0..7
        int grp = tid & 3;       // 0..3
        const float* lg = sm + lb*NPAD + grp*10;
        float v[10]; float mx = -1e30f;
        #pragma unroll
        for (int q = 0; q < 10; ++q){ v[q] = lg[q]; mx = fmaxf(mx, v[q]); }
        float e[10]; float s = 0.f;
        #pragma unroll
        for (int q = 0; q < 10; ++q){ e[q] = __expf(v[q]-mx); s += e[q]; }
        float inv = 1.0f/s;
        size_t b = (size_t)blockIdx.x*8 + lb;
        #pragma unroll
        for (int q = 0; q < 10; ++q) out[b*NCLS + grp*10 + q] = e[q]*inv;
    }
}

// ---------------------------------------------------------------------------
extern "C" void kernel_launch(void* const* d_in, const int* in_sizes, int n_in,
                              void* d_out, int out_size, void* d_ws, size_t ws_size,
                              hipStream_t stream)
{
    const float* x    = (const float*)d_in[0];
    const float* Wih  = (const float*)d_in[1];
    // d_in[2] = W_hh unused (zero initial hidden state)
    const float* bih  = (const float*)d_in[3];
    const float* bhh  = (const float*)d_in[4];
    const float* W2   = (const float*)d_in[5];
    const float* bout = (const float*)d_in[6];
    float* out = (float*)d_out;

    char* ws = (char*)d_ws;
    size_t off = 0;
    auto alloc = [&](size_t bytes){ void* p = ws + off; off = (off + bytes + 255) & ~(size_t)255; return p; };
    __bf16* h     = (__bf16*)alloc((size_t)MM*DD*2);           // 88.5 MB
    float*  part2 = (float*) alloc((size_t)KS2*BB*NPAD*4);     // 17.7 MB
    __bf16* wtb   = (__bf16*)alloc(288*104*2);                 // 60 KB
    __bf16* w2hi  = (__bf16*)alloc((size_t)NPAD*KDIM*2);       // 2.1 MB
    __bf16* w2lo  = (__bf16*)alloc((size_t)NPAD*KDIM*2);       // 2.1 MB

    pack1<<<15, 256, 0, stream>>>(Wih, bih, bhh, wtb);
    pack2<<<(NPAD*2700 + 255)/256, 256, 0, stream>>>(W2, w2hi, w2lo);
    k1_gates<<<512, 512, 0, stream>>>(x, wtb, h);
    k2_out<<<dim3(16, KS2), 256, 0, stream>>>(h, w2hi, w2lo, part2);
    k3<<<BB/8, 384, 0, stream>>>(part2, bout, out);
}

// Round 15
// 121.932 us; speedup vs baseline: 2.8570x; 1.0789x over previous
//
#include <hip/hip_runtime.h>
#include <hip/hip_bf16.h>

#define BB   2048
#define TT   240
#define DD   90
#define MM   (BB*TT)          // 491520
#define KDIM (TT*DD)          // 21600
#define NCLS 40
#define NPAD 48               // k2 N padded to 3 MFMA col-tiles
#define KS2  45               // k2 split-K chunks
#define KST  15               // k-steps (x32) per chunk: 45*15*32 = 21600

typedef __bf16 bf16x8 __attribute__((ext_vector_type(8)));
typedef float  f32x4  __attribute__((ext_vector_type(4)));

#define LOG2E  1.44269504f
#define LOG2E2 2.88539008f

__device__ __forceinline__ bf16x8 cvt8(float4 a, float4 b){
    bf16x8 r;
    r[0]=(__bf16)a.x; r[1]=(__bf16)a.y; r[2]=(__bf16)a.z; r[3]=(__bf16)a.w;
    r[4]=(__bf16)b.x; r[5]=(__bf16)b.y; r[6]=(__bf16)b.z; r[7]=(__bf16)b.w;
    return r;
}

__device__ __forceinline__ unsigned pack_bf16(float a, float b){
    unsigned u0 = (unsigned)__builtin_bit_cast(unsigned short, (__bf16)a);
    unsigned u1 = (unsigned)__builtin_bit_cast(unsigned short, (__bf16)b);
    return u0 | (u1 << 16);
}

// ---------------------------------------------------------------------------
// pack1 (r14-verified): Wtb[c][k] bf16, c = g*96+dd (gates i,g,o), k padded
// 90->104. Rows PRE-SCALED by exp2 constants (i,o: -log2e; g: 2*log2e).
// k=90: bias-hi, k=91: bias-lo (scaled); x-frag supplies 1.0 there.
// ---------------------------------------------------------------------------
__global__ void pack1(const float* __restrict__ Wih,
                      const float* __restrict__ bih,
                      const float* __restrict__ bhh,
                      __bf16* __restrict__ wtb)
{
    int id = blockIdx.x*256 + threadIdx.x;
    if (id >= 288*13) return;
    int c  = id / 13;
    int k8 = id - c*13;
    int g  = c / 96, dd = c - g*96;
    int row = (g==0 ? dd : (g==1 ? 180+dd : 270+dd));
    float scale = (g==1) ? LOG2E2 : -LOG2E;
    float bv = 0.f, bhi = 0.f, blo = 0.f;
    if (dd < 90){
        bv  = scale * (bih[row] + bhh[row]);
        bhi = (float)(__bf16)bv;
        blo = bv - bhi;
    }
    bf16x8 v;
    #pragma unroll
    for (int e = 0; e < 8; ++e){
        int k = k8*8 + e;
        float f = 0.f;
        if (dd < 90){
            if (k < 90)       f = scale * Wih[row*90 + k];
            else if (k == 90) f = bhi;
            else if (k == 91) f = blo;
        }
        v[e] = (__bf16)f;
    }
    *(bf16x8*)(wtb + c*104 + k8*8) = v;
}

// ---------------------------------------------------------------------------
// pack2: W_out -> bf16, hi only. [48][21600]. (lo term dropped: W2 quant
// error is zero-mean independent -> logit err ~3e-4, well under threshold.)
// ---------------------------------------------------------------------------
__global__ void pack2(const float* __restrict__ W2, __bf16* __restrict__ w2b)
{
    int id = blockIdx.x*256 + threadIdx.x;
    if (id >= NPAD*2700) return;
    int n  = id / 2700;
    int k8 = id - n*2700;
    bf16x8 v;
    if (n < NCLS){
        #pragma unroll
        for (int e = 0; e < 8; ++e)
            v[e] = (__bf16)W2[(size_t)n*KDIM + k8*8 + e];
    } else {
        #pragma unroll
        for (int e = 0; e < 8; ++e) v[e] = (__bf16)0.f;
    }
    *(bf16x8*)(w2b + (size_t)n*KDIM + k8*8) = v;
}

// ---------------------------------------------------------------------------
// k1: r14 VERBATIM (105-us verified config: W in LDS stride 104,
// launch_bounds(512,2) -> VGPR 96 no spill, single-buffer prefetch,
// C^T MFMA orientation, direct-exp2 epilogue on pre-scaled accumulators).
// ---------------------------------------------------------------------------
__global__ __launch_bounds__(512, 2)
void k1_gates(const float* __restrict__ x,
              const __bf16* __restrict__ wtb,
              __bf16* __restrict__ h)
{
    __shared__ __align__(16) __bf16 wt[288*104];   // 59904 B

    const int tid  = threadIdx.x;
    const int lane = tid & 63;
    const int wv   = tid >> 6;      // 0..7
    const int rg   = wv >> 1;       // row group 0..3
    const int nh   = wv & 1;        // N half 0..1
    const int l15  = lane & 15;
    const int kg   = lane >> 4;     // 0..3

    {
        const float4* src = (const float4*)wtb;
        float4* dst = (float4*)wt;
        #pragma unroll
        for (int i = 0; i < 8; ++i){
            int idx = tid + i*512;
            if (idx < 3744) dst[idx] = src[idx];
        }
    }
    __syncthreads();

    const int tbase = blockIdx.x * 15;     // 512 blocks * 15 tiles * 64 rows

    float4 xr[6];
    float2 xe;
    {
        const float* p = x + ((size_t)tbase*64 + rg*16 + l15)*90;
        #pragma unroll
        for (int ks = 0; ks < 2; ++ks){
            xr[ks*2+0] = *(const float4*)(p + ks*32 + kg*8);
            xr[ks*2+1] = *(const float4*)(p + ks*32 + kg*8 + 4);
        }
        if (kg < 3){
            xr[4] = *(const float4*)(p + 64 + kg*8);
            xr[5] = *(const float4*)(p + 64 + kg*8 + 4);
        } else {
            xe = *(const float2*)(p + 88);
        }
    }

    for (int t = 0; t < 15; ++t){
        bf16x8 af[3];
        af[0] = cvt8(xr[0], xr[1]);
        af[1] = cvt8(xr[2], xr[3]);
        if (kg < 3){
            af[2] = cvt8(xr[4], xr[5]);
        } else {
            bf16x8 z;
            #pragma unroll
            for (int e = 0; e < 8; ++e) z[e] = (__bf16)0.f;
            z[0] = (__bf16)xe.x; z[1] = (__bf16)xe.y;
            z[2] = (__bf16)1.0f; z[3] = (__bf16)1.0f;
            af[2] = z;
        }

        f32x4 acc[3][3];
        #pragma unroll
        for (int g = 0; g < 3; ++g)
            #pragma unroll
            for (int j = 0; j < 3; ++j) acc[g][j] = f32x4{0.f,0.f,0.f,0.f};

        const __bf16* wbase = wt + (nh*48 + l15)*104 + 8*kg;
        #pragma unroll
        for (int g = 0; g < 3; ++g){
            #pragma unroll
            for (int j = 0; j < 3; ++j){
                const __bf16* wrow = wbase + (g*96 + j*16)*104;
                #pragma unroll
                for (int ks = 0; ks < 3; ++ks){
                    bf16x8 wv8 = *(const bf16x8*)(wrow + ks*32);
                    acc[g][j] = __builtin_amdgcn_mfma_f32_16x16x32_bf16(wv8, af[ks], acc[g][j], 0,0,0);
                }
            }
        }

        if (t < 14){
            const float* p = x + ((size_t)(tbase+t+1)*64 + rg*16 + l15)*90;
            #pragma unroll
            for (int ks = 0; ks < 2; ++ks){
                xr[ks*2+0] = *(const float4*)(p + ks*32 + kg*8);
                xr[ks*2+1] = *(const float4*)(p + ks*32 + kg*8 + 4);
            }
            if (kg < 3){
                xr[4] = *(const float4*)(p + 64 + kg*8);
                xr[5] = *(const float4*)(p + 64 + kg*8 + 4);
            } else {
                xe = *(const float2*)(p + 88);
            }
        }

        // epilogue: accs pre-scaled -> exp2f args direct
        const size_t mrow = (size_t)(tbase+t)*64 + rg*16 + l15;
        __bf16* hp = h + mrow*90;
        #pragma unroll
        for (int j = 0; j < 3; ++j){
            int dd0 = nh*48 + j*16 + kg*4;
            float hv[4];
            #pragma unroll
            for (int r = 0; r < 4; ++r){
                float ea = exp2f(acc[0][j][r]);
                float Eg = exp2f(acc[1][j][r]);
                float cc = (Eg - 1.f) * __builtin_amdgcn_rcpf((1.f + ea)*(Eg + 1.f));
                float eo = exp2f(acc[2][j][r]);
                float Ec = exp2f(LOG2E2*cc);
                hv[r] = (Ec - 1.f) * __builtin_amdgcn_rcpf((1.f + eo)*(Ec + 1.f));
            }
            if (dd0 < 90)
                *(unsigned*)(hp + dd0) = pack_bf16(hv[0], hv[1]);
            if (dd0 + 2 < 90)
                *(unsigned*)(hp + dd0 + 2) = pack_bf16(hv[2], hv[3]);
        }
    }
}

// ---------------------------------------------------------------------------
// k2: out GEMM [2048 x 21600] @ [21600 x 48] via MFMA, split-K 45.
// hi-only W2 (6 MFMA + 5 loads per k-step, was 12 + 8).
// ---------------------------------------------------------------------------
__global__ __launch_bounds__(256)
void k2_out(const __bf16* __restrict__ h,
            const __bf16* __restrict__ w2b,
            float* __restrict__ part2)
{
    const int tid  = threadIdx.x;
    const int lane = tid & 63;
    const int wv   = tid >> 6;
    const int l15  = lane & 15;
    const int kg   = lane >> 4;
    const int m0   = (blockIdx.x*4 + wv) * 32;       // 0..2016
    const int chunk= blockIdx.y;                     // 0..44
    const size_t kbase = (size_t)chunk*(KST*32) + 8*kg;

    const __bf16* ha = h   + (size_t)(m0 + l15)*KDIM + kbase;
    const __bf16* hb = ha  + (size_t)16*KDIM;
    const __bf16* w0 = w2b + (size_t)l15*KDIM + kbase;
    const __bf16* w1 = w0  + (size_t)16*KDIM;
    const __bf16* w2 = w0  + (size_t)32*KDIM;

    f32x4 acc00 = {0.f,0.f,0.f,0.f}, acc01 = acc00, acc02 = acc00;
    f32x4 acc10 = acc00, acc11 = acc00, acc12 = acc00;

    #pragma unroll
    for (int s = 0; s < KST; ++s){
        bf16x8 a0 = *(const bf16x8*)(ha + s*32);
        bf16x8 a1 = *(const bf16x8*)(hb + s*32);
        bf16x8 b0 = *(const bf16x8*)(w0 + s*32);
        bf16x8 b1 = *(const bf16x8*)(w1 + s*32);
        bf16x8 b2 = *(const bf16x8*)(w2 + s*32);
        acc00 = __builtin_amdgcn_mfma_f32_16x16x32_bf16(a0, b0, acc00, 0,0,0);
        acc01 = __builtin_amdgcn_mfma_f32_16x16x32_bf16(a0, b1, acc01, 0,0,0);
        acc02 = __builtin_amdgcn_mfma_f32_16x16x32_bf16(a0, b2, acc02, 0,0,0);
        acc10 = __builtin_amdgcn_mfma_f32_16x16x32_bf16(a1, b0, acc10, 0,0,0);
        acc11 = __builtin_amdgcn_mfma_f32_16x16x32_bf16(a1, b1, acc11, 0,0,0);
        acc12 = __builtin_amdgcn_mfma_f32_16x16x32_bf16(a1, b2, acc12, 0,0,0);
    }

    float* pp = part2 + (size_t)chunk*(BB*NPAD);
    const int rbase = kg*4;
    #pragma unroll
    for (int r = 0; r < 4; ++r){
        size_t row0 = (size_t)(m0 + rbase + r)*NPAD;
        size_t row1 = (size_t)(m0 + 16 + rbase + r)*NPAD;
        pp[row0 +      l15] = acc00[r];
        pp[row0 + 16 + l15] = acc01[r];
        pp[row0 + 32 + l15] = acc02[r];
        pp[row1 +      l15] = acc10[r];
        pp[row1 + 16 + l15] = acc11[r];
        pp[row1 + 32 + l15] = acc12[r];
    }
}

// ---------------------------------------------------------------------------
// k3 (fused): reduce split-K partials + bias, then softmax over groups of 10.
// ---------------------------------------------------------------------------
__global__ __launch_bounds__(384)
void k3(const float* __restrict__ part2,
        const float* __restrict__ bout,
        float* __restrict__ out)
{
    __shared__ float sm[8*NPAD];
    const int tid  = threadIdx.x;
    const int base = blockIdx.x * 8 * NPAD;      // flat (b*48+n) base

    {
        int g = base + tid;
        float s = 0.f;
        for (int c = 0; c < KS2; ++c) s += part2[(size_t)c*(BB*NPAD) + g];
        int n = tid % NPAD;
        sm[tid] = s + (n < NCLS ? bout[n] : 0.f);
    }
    __syncthreads();

    if (tid < 32){
        int lb  = tid >> 2;      // 0..7
        int grp = tid & 3;       // 0..3
        const float* lg = sm + lb*NPAD + grp*10;
        float v[10]; float mx = -1e30f;
        #pragma unroll
        for (int q = 0; q < 10; ++q){ v[q] = lg[q]; mx = fmaxf(mx, v[q]); }
        float e[10]; float s = 0.f;
        #pragma unroll
        for (int q = 0; q < 10; ++q){ e[q] = __expf(v[q]-mx); s += e[q]; }
        float inv = 1.0f/s;
        size_t b = (size_t)blockIdx.x*8 + lb;
        #pragma unroll
        for (int q = 0; q < 10; ++q) out[b*NCLS + grp*10 + q] = e[q]*inv;
    }
}

// ---------------------------------------------------------------------------
extern "C" void kernel_launch(void* const* d_in, const int* in_sizes, int n_in,
                              void* d_out, int out_size, void* d_ws, size_t ws_size,
                              hipStream_t stream)
{
    const float* x    = (const float*)d_in[0];
    const float* Wih  = (const float*)d_in[1];
    // d_in[2] = W_hh unused (zero initial hidden state)
    const float* bih  = (const float*)d_in[3];
    const float* bhh  = (const float*)d_in[4];
    const float* W2   = (const float*)d_in[5];
    const float* bout = (const float*)d_in[6];
    float* out = (float*)d_out;

    char* ws = (char*)d_ws;
    size_t off = 0;
    auto alloc = [&](size_t bytes){ void* p = ws + off; off = (off + bytes + 255) & ~(size_t)255; return p; };
    __bf16* h     = (__bf16*)alloc((size_t)MM*DD*2);           // 88.5 MB
    float*  part2 = (float*) alloc((size_t)KS2*BB*NPAD*4);     // 17.7 MB
    __bf16* wtb   = (__bf16*)alloc(288*104*2);                 // 60 KB
    __bf16* w2b   = (__bf16*)alloc((size_t)NPAD*KDIM*2);       // 2.1 MB

    pack1<<<15, 256, 0, stream>>>(Wih, bih, bhh, wtb);
    pack2<<<(NPAD*2700 + 255)/256, 256, 0, stream>>>(W2, w2b);
    k1_gates<<<512, 512, 0, stream>>>(x, wtb, h);
    k2_out<<<dim3(16, KS2), 256, 0, stream>>>(h, w2b, part2);
    k3<<<BB/8, 384, 0, stream>>>(part2, bout, out);
}